// Round 3
// baseline (1216.442 us; speedup 1.0000x reference)
//
#include <hip/hip_runtime.h>
#include <stdint.h>

// Round 3: algorithm unchanged from R1/R2. All scratch moved from d_ws into
// the d_out[0 : N*N] decoder region (written only by the final kernel) —
// d_ws is now completely unused, eliminating any ws_size-overflow crash.
// z is read by the decoder as fp32 (= mu, in the d_out tail) and converted
// to bf16 fragments in-register.

#define NN 12288   // nodes
#define FF 512     // input feature dim
#define HD1 256    // hidden 1
#define HD2 128    // latent
#define EE 393216  // edges  (EE % 256 == 0)

typedef short bf16x8 __attribute__((ext_vector_type(8)));   // 8 bf16 in 4 VGPRs
typedef float f32x16 __attribute__((ext_vector_type(16)));

__device__ inline unsigned short f2b(float f) {
  // fp32 -> bf16 round-to-nearest-even (inputs finite)
  unsigned int u = __float_as_uint(f);
  unsigned int r = u + 0x7fffu + ((u >> 16) & 1u);
  return (unsigned short)(r >> 16);
}

__device__ inline bf16x8 ldb8(const unsigned short* p) {
  return *(const bf16x8*)p;
}

// load 8 fp32, convert to bf16 fragment
__device__ inline bf16x8 ldf8(const float* p) {
  float4 v0 = ((const float4*)p)[0];
  float4 v1 = ((const float4*)p)[1];
  bf16x8 r;
  r[0] = (short)f2b(v0.x); r[1] = (short)f2b(v0.y);
  r[2] = (short)f2b(v0.z); r[3] = (short)f2b(v0.w);
  r[4] = (short)f2b(v1.x); r[5] = (short)f2b(v1.y);
  r[6] = (short)f2b(v1.z); r[7] = (short)f2b(v1.w);
  return r;
}

__device__ inline f32x16 mfma32(bf16x8 a, bf16x8 b, f32x16 c) {
  return __builtin_amdgcn_mfma_f32_32x32x16_bf16(a, b, c, 0, 0, 0);
}

// ---------------- CSR build ----------------

__global__ void k_hist(const int* __restrict__ src, int* __restrict__ deg) {
  int e = blockIdx.x * 256 + threadIdx.x;   // EE multiple of 256
  atomicAdd(&deg[src[e]], 1);
}

__global__ void k_scan(const int* __restrict__ deg, int* __restrict__ off,
                       int* __restrict__ cur) {
  __shared__ int sdata[256];
  __shared__ int sbase;
  if (threadIdx.x == 0) sbase = 0;
  __syncthreads();
  for (int c = 0; c < NN; c += 256) {   // NN multiple of 256
    int v = deg[c + threadIdx.x];
    sdata[threadIdx.x] = v;
    __syncthreads();
    for (int s = 1; s < 256; s <<= 1) {
      int t = (threadIdx.x >= s) ? sdata[threadIdx.x - s] : 0;
      __syncthreads();
      sdata[threadIdx.x] += t;
      __syncthreads();
    }
    int o = sbase + sdata[threadIdx.x] - v;
    off[c + threadIdx.x] = o;
    cur[c + threadIdx.x] = o;
    __syncthreads();
    if (threadIdx.x == 255) sbase += sdata[255];
    __syncthreads();
  }
}

__global__ void k_fill(const int* __restrict__ src, int* __restrict__ cur,
                       int* __restrict__ eidx) {
  int e = blockIdx.x * 256 + threadIdx.x;
  int p = atomicAdd(&cur[src[e]], 1);
  eidx[p] = e;
}

// ---------------- dtype prep ----------------

__global__ void k_f2b4(const float* __restrict__ in, unsigned short* __restrict__ outb) {
  int i = blockIdx.x * 256 + threadIdx.x;   // each thread converts 4
  float4 v = ((const float4*)in)[i];
  ushort4 o;
  o.x = f2b(v.x); o.y = f2b(v.y); o.z = f2b(v.z); o.w = f2b(v.w);
  ((ushort4*)outb)[i] = o;
}

// W [K, Ncols] fp32 row-major -> Wt [Ncols, K] bf16 row-major
__global__ void k_transw(const float* __restrict__ W, unsigned short* __restrict__ Wt,
                         int K, int Ncols) {
  int idx = blockIdx.x * 256 + threadIdx.x;
  if (idx < K * Ncols) {
    int k = idx / Ncols;
    int n = idx - k * Ncols;
    Wt[(size_t)n * K + k] = f2b(W[idx]);
  }
}

// ---------------- GEMM: C[M,Nn] = A[M,K] * Bt[Nn,K]^T  (bf16 in, fp32 out) ----------------

__global__ __launch_bounds__(256) void gemm_bt(
    const unsigned short* __restrict__ A, const unsigned short* __restrict__ Bt,
    float* __restrict__ C, int Nn, int K) {
  int wave = threadIdx.x >> 6, lane = threadIdx.x & 63;
  int wr = wave >> 1, wc = wave & 1;
  int row0 = blockIdx.x * 128 + wr * 64;
  int col0 = blockIdx.y * 128 + wc * 64;
  int lm = lane & 31, lk = (lane >> 5) * 8;

  f32x16 acc[2][2] = {};
  const unsigned short* a0p = A + (size_t)(row0 + lm) * K + lk;
  const unsigned short* a1p = a0p + (size_t)32 * K;
  const unsigned short* b0p = Bt + (size_t)(col0 + lm) * K + lk;
  const unsigned short* b1p = b0p + (size_t)32 * K;

  for (int k0 = 0; k0 < K; k0 += 16) {
    bf16x8 a0 = ldb8(a0p + k0), a1 = ldb8(a1p + k0);
    bf16x8 b0 = ldb8(b0p + k0), b1 = ldb8(b1p + k0);
    acc[0][0] = mfma32(a0, b0, acc[0][0]);
    acc[0][1] = mfma32(a0, b1, acc[0][1]);
    acc[1][0] = mfma32(a1, b0, acc[1][0]);
    acc[1][1] = mfma32(a1, b1, acc[1][1]);
  }

#pragma unroll
  for (int ti = 0; ti < 2; ++ti)
#pragma unroll
    for (int tj = 0; tj < 2; ++tj)
#pragma unroll
      for (int r = 0; r < 16; ++r) {
        int row = row0 + ti * 32 + (r & 3) + 8 * (r >> 2) + 4 * (lane >> 5);
        int col = col0 + tj * 32 + lm;
        C[(size_t)row * Nn + col] = acc[ti][tj][r];
      }
}

// ---------------- SpMM (CSR gather) ----------------

// h1b[i,:] = bf16(relu( sum_e val[e]*sup1[dst[e],:] )), D = 256
__global__ void k_spmm_relu(const int* __restrict__ off, const int* __restrict__ eidx,
                            const int* __restrict__ dst, const float* __restrict__ val,
                            const float* __restrict__ dense,
                            unsigned short* __restrict__ outb) {
  int i = blockIdx.x;
  int d = threadIdx.x;
  int e0 = off[i];
  int e1 = (i == NN - 1) ? EE : off[i + 1];
  float acc = 0.f;
  for (int e = e0; e < e1; ++e) {
    int ee = eidx[e];
    acc += val[ee] * dense[(size_t)dst[ee] * HD1 + d];
  }
  outb[(size_t)i * HD1 + d] = f2b(fmaxf(acc, 0.f));
}

// mu/logvar from sup23 [N, 256]; write fp32 to d_out tail
__global__ void k_spmm_mlv(const int* __restrict__ off, const int* __restrict__ eidx,
                           const int* __restrict__ dst, const float* __restrict__ val,
                           const float* __restrict__ dense,
                           float* __restrict__ mu, float* __restrict__ logvar) {
  int i = blockIdx.x;
  int d = threadIdx.x;
  int e0 = off[i];
  int e1 = (i == NN - 1) ? EE : off[i + 1];
  float acc = 0.f;
  for (int e = e0; e < e1; ++e) {
    int ee = eidx[e];
    acc += val[ee] * dense[(size_t)dst[ee] * (2 * HD2) + d];
  }
  if (d < HD2) mu[(size_t)i * HD2 + d] = acc;
  else         logvar[(size_t)i * HD2 + (d - HD2)] = acc;
}

// ---------------- Decoder: out = sigmoid(Z * Z^T), Z = mu [NN, 128] fp32 ----------------

__global__ __launch_bounds__(256) void k_decoder(const float* __restrict__ Zf,
                                                 float* __restrict__ out) {
  int wave = threadIdx.x >> 6, lane = threadIdx.x & 63;
  int wr = wave >> 1, wc = wave & 1;
  int row0 = blockIdx.x * 128 + wr * 64;
  int col0 = blockIdx.y * 128 + wc * 64;
  int lm = lane & 31, lk = (lane >> 5) * 8;

  f32x16 acc[2][2] = {};
  const float* a0p = Zf + (size_t)(row0 + lm) * HD2 + lk;
  const float* a1p = a0p + (size_t)32 * HD2;
  const float* b0p = Zf + (size_t)(col0 + lm) * HD2 + lk;
  const float* b1p = b0p + (size_t)32 * HD2;

#pragma unroll
  for (int k0 = 0; k0 < HD2; k0 += 16) {
    bf16x8 a0 = ldf8(a0p + k0), a1 = ldf8(a1p + k0);
    bf16x8 b0 = ldf8(b0p + k0), b1 = ldf8(b1p + k0);
    acc[0][0] = mfma32(a0, b0, acc[0][0]);
    acc[0][1] = mfma32(a0, b1, acc[0][1]);
    acc[1][0] = mfma32(a1, b0, acc[1][0]);
    acc[1][1] = mfma32(a1, b1, acc[1][1]);
  }

#pragma unroll
  for (int ti = 0; ti < 2; ++ti)
#pragma unroll
    for (int tj = 0; tj < 2; ++tj)
#pragma unroll
      for (int r = 0; r < 16; ++r) {
        int row = row0 + ti * 32 + (r & 3) + 8 * (r >> 2) + 4 * (lane >> 5);
        int col = col0 + tj * 32 + lm;
        float v = acc[ti][tj][r];
        out[(size_t)row * NN + col] = 1.0f / (1.0f + __expf(-v));
      }
}

// ---------------- launch ----------------

extern "C" void kernel_launch(void* const* d_in, const int* in_sizes, int n_in,
                              void* d_out, int out_size, void* d_ws, size_t ws_size,
                              hipStream_t stream) {
  const float* x  = (const float*)d_in[0];
  const int*   src = (const int*)d_in[1];
  const int*   dst = (const int*)d_in[2];
  const float* ev  = (const float*)d_in[3];
  const float* W1  = (const float*)d_in[4];
  const float* W2  = (const float*)d_in[5];
  const float* W3  = (const float*)d_in[6];
  float* out = (float*)d_out;
  float* mu     = out + (size_t)NN * NN;
  float* logvar = mu + (size_t)NN * HD2;

  // Scratch lives inside out[0 : NN*NN] (604 MB; we need ~46 MB). Every
  // scratch byte is dead before k_decoder overwrites the region. d_ws unused.
  char* p = (char*)d_out;
  auto alloc = [&](size_t bytes) {
    char* r = p;
    p += (bytes + 255) & ~(size_t)255;
    return r;
  };
  unsigned short* xb   = (unsigned short*)alloc((size_t)NN * FF * 2);
  unsigned short* W1t  = (unsigned short*)alloc((size_t)HD1 * FF * 2);
  unsigned short* W23t = (unsigned short*)alloc((size_t)2 * HD2 * HD1 * 2);
  float*          sup1 = (float*)alloc((size_t)NN * HD1 * 4);
  unsigned short* h1b  = (unsigned short*)alloc((size_t)NN * HD1 * 2);
  float*         sup23 = (float*)alloc((size_t)NN * 2 * HD2 * 4);
  int* deg  = (int*)alloc(NN * 4);
  int* off  = (int*)alloc(NN * 4);
  int* cur  = (int*)alloc(NN * 4);
  int* eidx = (int*)alloc((size_t)EE * 4);

  // CSR build on src
  hipMemsetAsync(deg, 0, NN * 4, stream);
  k_hist<<<EE / 256, 256, 0, stream>>>(src, deg);
  k_scan<<<1, 256, 0, stream>>>(deg, off, cur);
  k_fill<<<EE / 256, 256, 0, stream>>>(src, cur, eidx);

  // dtype prep
  k_f2b4<<<(NN * FF / 4) / 256, 256, 0, stream>>>(x, xb);
  k_transw<<<(FF * HD1 + 255) / 256, 256, 0, stream>>>(W1, W1t, FF, HD1);
  k_transw<<<(HD1 * HD2 + 255) / 256, 256, 0, stream>>>(W2, W23t, HD1, HD2);
  k_transw<<<(HD1 * HD2 + 255) / 256, 256, 0, stream>>>(W3, W23t + (size_t)HD2 * HD1, HD1, HD2);

  // encoder layer 1: sup1 = x @ W1 ; h1 = relu(spmm(sup1))
  gemm_bt<<<dim3(NN / 128, HD1 / 128), 256, 0, stream>>>(xb, W1t, sup1, HD1, FF);
  k_spmm_relu<<<NN, 256, 0, stream>>>(off, eidx, dst, ev, sup1, h1b);

  // encoder layer 2 (mu|logvar fused): sup23 = h1 @ [W2|W3] ; spmm -> mu,logvar
  gemm_bt<<<dim3(NN / 128, (2 * HD2) / 128), 256, 0, stream>>>(h1b, W23t, sup23, 2 * HD2, HD1);
  k_spmm_mlv<<<NN, 256, 0, stream>>>(off, eidx, dst, ev, sup23, mu, logvar);

  // decoder: out[0 : NN*NN] = sigmoid(mu @ mu^T)  (z = mu in eval mode)
  k_decoder<<<dim3(NN / 128, NN / 128), 256, 0, stream>>>(mu, out);
}